// Round 4
// baseline (1864.136 us; speedup 1.0000x reference)
//
#include <hip/hip_runtime.h>
#include <math.h>

#define TOKENS   8192
#define DMODEL   1024
#define HDIM     2048
#define NEXP     8
#define NSH      2
#define NGRP     10
#define R_ROUTED 16384
#define R_TOTAL  32768

typedef float  f32x4  __attribute__((ext_vector_type(4)));
typedef __bf16 bf16x8 __attribute__((ext_vector_type(8)));
typedef unsigned short u16x8 __attribute__((ext_vector_type(8)));

typedef __attribute__((address_space(1))) const void as1_void;
typedef __attribute__((address_space(3))) void as3_void;
#define GLOAD16(g, l) __builtin_amdgcn_global_load_lds((as1_void*)(g), (as3_void*)(l), 16, 0, 0)

__device__ __forceinline__ unsigned short f2bf(float f) {
  unsigned int u = __float_as_uint(f);
  u += 0x7fffu + ((u >> 16) & 1u);
  return (unsigned short)(u >> 16);
}

// ---------------- conversion kernels ----------------

__global__ __launch_bounds__(256) void convert_x_kernel(const float* __restrict__ x,
                                                        unsigned short* __restrict__ xb) {
  int i = blockIdx.x * blockDim.x + threadIdx.x;
  const float4 v = reinterpret_cast<const float4*>(x)[i];
  ushort4 o;
  o.x = f2bf(v.x); o.y = f2bf(v.y); o.z = f2bf(v.z); o.w = f2bf(v.w);
  reinterpret_cast<ushort4*>(xb)[i] = o;
}

// transpose fp32 (R x C) -> bf16 (C x R), 64x64 tiles, vectorized both sides
__global__ __launch_bounds__(256) void transpose_cvt64_kernel(const float* __restrict__ src,
                                                              unsigned short* __restrict__ dst,
                                                              int R, int C) {
  __shared__ float tile[64][65];
  const size_t mat = blockIdx.z;
  src += mat * (size_t)R * C;
  dst += mat * (size_t)R * C;
  const int c0 = blockIdx.x * 64, r0 = blockIdx.y * 64;
  const int tid = threadIdx.x;
  const int tx = tid & 15, ty = tid >> 4;     // 16 x 16
  #pragma unroll
  for (int rr = 0; rr < 4; ++rr) {
    const int row = ty + rr * 16;
    const float4 v = *reinterpret_cast<const float4*>(&src[(size_t)(r0 + row) * C + c0 + tx * 4]);
    tile[row][tx * 4 + 0] = v.x;
    tile[row][tx * 4 + 1] = v.y;
    tile[row][tx * 4 + 2] = v.z;
    tile[row][tx * 4 + 3] = v.w;
  }
  __syncthreads();
  const int oc = tid >> 2, og = tid & 3;      // col 0..63, r-quarter 0..3
  u16x8 u0, u1;
  #pragma unroll
  for (int e = 0; e < 8; ++e) u0[e] = f2bf(tile[og * 16 + e][oc]);
  #pragma unroll
  for (int e = 0; e < 8; ++e) u1[e] = f2bf(tile[og * 16 + 8 + e][oc]);
  unsigned short* dp = &dst[(size_t)(c0 + oc) * R + r0 + og * 16];
  *reinterpret_cast<u16x8*>(dp) = u0;
  *reinterpret_cast<u16x8*>(dp + 8) = u1;
}

// ---------------- gating / routing ----------------

__global__ __launch_bounds__(64) void gate_kernel(const float* __restrict__ x,
                                                  const float* __restrict__ gw,
                                                  const float* __restrict__ gb,
                                                  int* __restrict__ topk_idx,
                                                  float* __restrict__ topk_w,
                                                  int* __restrict__ counts) {
  const int t = blockIdx.x;
  const int lane = threadIdx.x;
  const float* xr = x + (size_t)t * DMODEL;
  float acc[NEXP];
  #pragma unroll
  for (int e = 0; e < NEXP; ++e) acc[e] = 0.f;
  for (int d = lane; d < DMODEL; d += 64) {
    const float xv = xr[d];
    const float* g = gw + (size_t)d * NEXP;
    #pragma unroll
    for (int e = 0; e < NEXP; ++e) acc[e] += xv * g[e];
  }
  #pragma unroll
  for (int e = 0; e < NEXP; ++e) {
    float v = acc[e];
    v += __shfl_down(v, 32); v += __shfl_down(v, 16); v += __shfl_down(v, 8);
    v += __shfl_down(v, 4);  v += __shfl_down(v, 2);  v += __shfl_down(v, 1);
    acc[e] = v;
  }
  if (lane == 0) {
    float p[NEXP];
    float mx = -1e30f;
    #pragma unroll
    for (int e = 0; e < NEXP; ++e) { acc[e] += gb[e]; mx = fmaxf(mx, acc[e]); }
    float s = 0.f;
    #pragma unroll
    for (int e = 0; e < NEXP; ++e) { p[e] = expf(acc[e] - mx); s += p[e]; }
    const float inv = 1.f / s;
    #pragma unroll
    for (int e = 0; e < NEXP; ++e) p[e] *= inv;
    int i1 = 0; float v1 = p[0];
    #pragma unroll
    for (int e = 1; e < NEXP; ++e) if (p[e] > v1) { v1 = p[e]; i1 = e; }
    int i2 = -1; float v2 = -1e30f;
    #pragma unroll
    for (int e = 0; e < NEXP; ++e) if (e != i1 && p[e] > v2) { v2 = p[e]; i2 = e; }
    topk_idx[t * 2 + 0] = i1; topk_w[t * 2 + 0] = v1;
    topk_idx[t * 2 + 1] = i2; topk_w[t * 2 + 1] = v2;
    atomicAdd(&counts[i1], 1);
    atomicAdd(&counts[i2], 1);
  }
}

__global__ void offs_kernel(const int* __restrict__ counts, int* __restrict__ offs) {
  if (threadIdx.x == 0 && blockIdx.x == 0) {
    int cum = 0;
    for (int e = 0; e < NEXP; ++e) { offs[e] = cum; cum += counts[e]; }
    offs[8] = R_ROUTED;
    offs[9] = R_ROUTED + TOKENS;
    offs[10] = R_TOTAL;
  }
}

__global__ __launch_bounds__(256) void scatter_kernel(const int* __restrict__ topk_idx,
                                                      const float* __restrict__ topk_w,
                                                      const int* __restrict__ offs,
                                                      int* __restrict__ cursors,
                                                      int* __restrict__ row_token,
                                                      float* __restrict__ row_coef) {
  const int t = blockIdx.x * blockDim.x + threadIdx.x;
  if (t >= TOKENS) return;
  #pragma unroll
  for (int k = 0; k < 2; ++k) {
    const int e = topk_idx[t * 2 + k];
    const int pos = atomicAdd(&cursors[e], 1);
    const int r = offs[e] + pos;
    row_token[r] = t;
    row_coef[r] = topk_w[t * 2 + k];
  }
  row_token[R_ROUTED + t] = t;          row_coef[R_ROUTED + t] = 0.5f;
  row_token[R_ROUTED + TOKENS + t] = t; row_coef[R_ROUTED + TOKENS + t] = 0.5f;
}

// ---- grouped GEMM 1 (2-phase dbuf, stage-early): glu = silu(XW1+b1)*(XW2+b2) ----
// BM=256, BN=128 (dual B), BK=64, 512 thr (8 waves, 2M x 4N), dbuf LDS 128 KiB.
// One __syncthreads per K-tile; stage(t+1 -> buf^1) issued before compute so the
// compiler's vmcnt(0)-before-barrier drain lands after the compute hides latency.
// T2 swizzle: LDS slot (row,j) holds global k-chunk j^(row&7).

__global__ __launch_bounds__(512, 2) void gemm1_kernel(
    const unsigned short* __restrict__ xb,
    const unsigned short* __restrict__ w1t,
    const unsigned short* __restrict__ w2t,
    const float* __restrict__ rb1, const float* __restrict__ sb1,
    const float* __restrict__ rb2, const float* __restrict__ sb2,
    const int* __restrict__ offs,
    const int* __restrict__ row_token,
    unsigned short* __restrict__ glu) {
  const int g = blockIdx.z;
  const int off_g = offs[g];
  const int n_g = offs[g + 1] - off_g;
  const int m0 = blockIdx.x * 256;
  if (m0 >= n_g) return;
  const int n0 = blockIdx.y * 128;

  __shared__ __align__(16) unsigned short Abuf[2][256 * 64];
  __shared__ __align__(16) unsigned short B1buf[2][128 * 64];
  __shared__ __align__(16) unsigned short B2buf[2][128 * 64];

  const int tid = threadIdx.x;
  const int lane = tid & 63;
  const int wid = tid >> 6;
  const int wm = wid >> 2, wn = wid & 3;
  const int l15 = lane & 15, kq = lane >> 4;

  const unsigned short* w1g = w1t + (size_t)g * HDIM * DMODEL;
  const unsigned short* w2g = w2t + (size_t)g * HDIM * DMODEL;

  const unsigned short* srcA[4]; int dA[4];
  #pragma unroll
  for (int r = 0; r < 4; ++r) {
    const int flat = r * 512 + tid, row = flat >> 3, j = flat & 7;
    int ar = m0 + row; if (ar > n_g - 1) ar = n_g - 1;
    srcA[r] = xb + (size_t)row_token[off_g + ar] * DMODEL + ((j ^ (row & 7)) << 3);
    dA[r] = (r * 512 + (tid & ~63)) << 3;
  }
  const unsigned short* srcB1[2]; const unsigned short* srcB2[2]; int dB[2];
  #pragma unroll
  for (int r = 0; r < 2; ++r) {
    const int flat = r * 512 + tid, row = flat >> 3, j = flat & 7;
    const size_t o = (size_t)(n0 + row) * DMODEL + ((j ^ (row & 7)) << 3);
    srcB1[r] = w1g + o; srcB2[r] = w2g + o;
    dB[r] = (r * 512 + (tid & ~63)) << 3;
  }

  f32x4 acc1[8][2], acc2[8][2];
  const f32x4 zero = {0.f, 0.f, 0.f, 0.f};
  #pragma unroll
  for (int i = 0; i < 8; ++i)
    #pragma unroll
    for (int j = 0; j < 2; ++j) { acc1[i][j] = zero; acc2[i][j] = zero; }

  auto stage = [&](int cur, int k0) {
    #pragma unroll
    for (int r = 0; r < 4; ++r) GLOAD16(srcA[r] + k0, &Abuf[cur][dA[r]]);
    #pragma unroll
    for (int r = 0; r < 2; ++r) {
      GLOAD16(srcB1[r] + k0, &B1buf[cur][dB[r]]);
      GLOAD16(srcB2[r] + k0, &B2buf[cur][dB[r]]);
    }
  };

  stage(0, 0);
  __syncthreads();

  for (int kt = 0; kt < 16; ++kt) {
    const int cur = kt & 1;
    if (kt + 1 < 16) stage(cur ^ 1, (kt + 1) * 64);
    #pragma unroll
    for (int ks = 0; ks < 2; ++ks) {
      const int kc = ks * 4 + kq;
      bf16x8 a[8], p[2], q[2];
      #pragma unroll
      for (int mi = 0; mi < 8; ++mi) {
        const int row = wm * 128 + mi * 16 + l15;
        a[mi] = *reinterpret_cast<const bf16x8*>(&Abuf[cur][row * 64 + ((kc ^ (row & 7)) << 3)]);
      }
      #pragma unroll
      for (int ni = 0; ni < 2; ++ni) {
        const int row = wn * 32 + ni * 16 + l15;
        p[ni] = *reinterpret_cast<const bf16x8*>(&B1buf[cur][row * 64 + ((kc ^ (row & 7)) << 3)]);
        q[ni] = *reinterpret_cast<const bf16x8*>(&B2buf[cur][row * 64 + ((kc ^ (row & 7)) << 3)]);
      }
      #pragma unroll
      for (int mi = 0; mi < 8; ++mi)
        #pragma unroll
        for (int ni = 0; ni < 2; ++ni) {
          acc1[mi][ni] = __builtin_amdgcn_mfma_f32_16x16x32_bf16(a[mi], p[ni], acc1[mi][ni], 0, 0, 0);
          acc2[mi][ni] = __builtin_amdgcn_mfma_f32_16x16x32_bf16(a[mi], q[ni], acc2[mi][ni], 0, 0, 0);
        }
    }
    __syncthreads();
  }

  const float* b1p = (g < NEXP) ? (rb1 + (size_t)g * HDIM) : (sb1 + (size_t)(g - NEXP) * HDIM);
  const float* b2p = (g < NEXP) ? (rb2 + (size_t)g * HDIM) : (sb2 + (size_t)(g - NEXP) * HDIM);

  #pragma unroll
  for (int mi = 0; mi < 8; ++mi) {
    #pragma unroll
    for (int r = 0; r < 4; ++r) {
      const int m = m0 + wm * 128 + mi * 16 + kq * 4 + r;
      if (m < n_g) {
        #pragma unroll
        for (int ni = 0; ni < 2; ++ni) {
          const int n = n0 + wn * 32 + ni * 16 + l15;
          const float x1 = acc1[mi][ni][r] + b1p[n];
          const float x2 = acc2[mi][ni][r] + b2p[n];
          glu[(size_t)(off_g + m) * HDIM + n] = f2bf((x1 / (1.f + expf(-x1))) * x2);
        }
      }
    }
  }
}

// ---- grouped GEMM 2 (2-phase dbuf, stage-early): out += coef * (glu W3 + b3) ----
// BM=256, BN=256, BK=64, 512 thr (8 waves, 2M x 4N), dbuf LDS 128 KiB.

__global__ __launch_bounds__(512, 2) void gemm2_kernel(
    const unsigned short* __restrict__ glu,
    const unsigned short* __restrict__ w3t,
    const float* __restrict__ rb3, const float* __restrict__ sb3,
    const int* __restrict__ offs,
    const int* __restrict__ row_token,
    const float* __restrict__ row_coef,
    float* __restrict__ out) {
  const int g = blockIdx.z;
  const int off_g = offs[g];
  const int n_g = offs[g + 1] - off_g;
  const int m0 = blockIdx.x * 256;
  if (m0 >= n_g) return;
  const int n0 = blockIdx.y * 256;

  __shared__ __align__(16) unsigned short Abuf[2][256 * 64];
  __shared__ __align__(16) unsigned short Bbuf[2][256 * 64];

  const int tid = threadIdx.x;
  const int lane = tid & 63;
  const int wid = tid >> 6;
  const int wm = wid >> 2, wn = wid & 3;
  const int l15 = lane & 15, kq = lane >> 4;

  const unsigned short* w3g = w3t + (size_t)g * DMODEL * HDIM;

  const unsigned short* srcA[4]; const unsigned short* srcB[4]; int dAB[4];
  #pragma unroll
  for (int r = 0; r < 4; ++r) {
    const int flat = r * 512 + tid, row = flat >> 3, j = flat & 7;
    int ar = m0 + row; if (ar > n_g - 1) ar = n_g - 1;
    srcA[r] = glu + (size_t)(off_g + ar) * HDIM + ((j ^ (row & 7)) << 3);
    srcB[r] = w3g + (size_t)(n0 + row) * HDIM + ((j ^ (row & 7)) << 3);
    dAB[r] = (r * 512 + (tid & ~63)) << 3;
  }

  f32x4 acc[8][4];
  const f32x4 zero = {0.f, 0.f, 0.f, 0.f};
  #pragma unroll
  for (int i = 0; i < 8; ++i)
    #pragma unroll
    for (int j = 0; j < 4; ++j) acc[i][j] = zero;

  auto stage = [&](int cur, int k0) {
    #pragma unroll
    for (int r = 0; r < 4; ++r) GLOAD16(srcA[r] + k0, &Abuf[cur][dAB[r]]);
    #pragma unroll
    for (int r = 0; r < 4; ++r) GLOAD16(srcB[r] + k0, &Bbuf[cur][dAB[r]]);
  };

  stage(0, 0);
  __syncthreads();

  for (int kt = 0; kt < 32; ++kt) {
    const int cur = kt & 1;
    if (kt + 1 < 32) stage(cur ^ 1, (kt + 1) * 64);
    #pragma unroll
    for (int ks = 0; ks < 2; ++ks) {
      const int kc = ks * 4 + kq;
      bf16x8 a[8], b[4];
      #pragma unroll
      for (int mi = 0; mi < 8; ++mi) {
        const int row = wm * 128 + mi * 16 + l15;
        a[mi] = *reinterpret_cast<const bf16x8*>(&Abuf[cur][row * 64 + ((kc ^ (row & 7)) << 3)]);
      }
      #pragma unroll
      for (int ni = 0; ni < 4; ++ni) {
        const int row = wn * 64 + ni * 16 + l15;
        b[ni] = *reinterpret_cast<const bf16x8*>(&Bbuf[cur][row * 64 + ((kc ^ (row & 7)) << 3)]);
      }
      #pragma unroll
      for (int mi = 0; mi < 8; ++mi)
        #pragma unroll
        for (int ni = 0; ni < 4; ++ni)
          acc[mi][ni] = __builtin_amdgcn_mfma_f32_16x16x32_bf16(a[mi], b[ni], acc[mi][ni], 0, 0, 0);
    }
    __syncthreads();
  }

  const float* b3p = (g < NEXP) ? (rb3 + (size_t)g * DMODEL) : (sb3 + (size_t)(g - NEXP) * DMODEL);

  #pragma unroll
  for (int mi = 0; mi < 8; ++mi) {
    #pragma unroll
    for (int r = 0; r < 4; ++r) {
      const int m = m0 + wm * 128 + mi * 16 + kq * 4 + r;
      if (m < n_g) {
        const int t = row_token[off_g + m];
        const float cf = row_coef[off_g + m];
        float* orow = out + (size_t)t * DMODEL;
        #pragma unroll
        for (int ni = 0; ni < 4; ++ni) {
          const int n = n0 + wn * 64 + ni * 16 + l15;
          atomicAdd(&orow[n], (acc[mi][ni][r] + b3p[n]) * cf);
        }
      }
    }
  }
}

// ---------------- launch ----------------

extern "C" void kernel_launch(void* const* d_in, const int* in_sizes, int n_in,
                              void* d_out, int out_size, void* d_ws, size_t ws_size,
                              hipStream_t stream) {
  const float* x      = (const float*)d_in[0];
  const float* gate_w = (const float*)d_in[1];
  const float* gate_b = (const float*)d_in[2];
  const float* rw1    = (const float*)d_in[3];
  const float* rb1    = (const float*)d_in[4];
  const float* rw2    = (const float*)d_in[5];
  const float* rb2    = (const float*)d_in[6];
  const float* rw3    = (const float*)d_in[7];
  const float* rb3    = (const float*)d_in[8];
  const float* sw1    = (const float*)d_in[9];
  const float* sb1    = (const float*)d_in[10];
  const float* sw2    = (const float*)d_in[11];
  const float* sb2    = (const float*)d_in[12];
  const float* sw3    = (const float*)d_in[13];
  const float* sb3    = (const float*)d_in[14];
  float* out = (float*)d_out;

  // workspace layout
  const size_t XB_OFF   = 0;
  const size_t W1T_OFF  = XB_OFF  + (size_t)TOKENS * DMODEL * 2;
  const size_t W2T_OFF  = W1T_OFF + (size_t)NGRP * HDIM * DMODEL * 2;
  const size_t W3T_OFF  = W2T_OFF + (size_t)NGRP * HDIM * DMODEL * 2;
  const size_t GLU_OFF  = W3T_OFF + (size_t)NGRP * DMODEL * HDIM * 2;
  const size_t RTOK_OFF = GLU_OFF + (size_t)R_TOTAL * HDIM * 2;
  const size_t RCOE_OFF = RTOK_OFF + (size_t)R_TOTAL * 4;
  const size_t TKI_OFF  = RCOE_OFF + (size_t)R_TOTAL * 4;
  const size_t TKW_OFF  = TKI_OFF + (size_t)TOKENS * 2 * 4;
  const size_t META_OFF = TKW_OFF + (size_t)TOKENS * 2 * 4;
  const size_t NEED     = META_OFF + 256;
  if (ws_size < NEED) return;

  char* ws = (char*)d_ws;
  unsigned short* xb   = (unsigned short*)(ws + XB_OFF);
  unsigned short* w1t  = (unsigned short*)(ws + W1T_OFF);
  unsigned short* w2t  = (unsigned short*)(ws + W2T_OFF);
  unsigned short* w3t  = (unsigned short*)(ws + W3T_OFF);
  unsigned short* glu  = (unsigned short*)(ws + GLU_OFF);
  int*   row_token = (int*)(ws + RTOK_OFF);
  float* row_coef  = (float*)(ws + RCOE_OFF);
  int*   topk_idx  = (int*)(ws + TKI_OFF);
  float* topk_w    = (float*)(ws + TKW_OFF);
  int*   counts    = (int*)(ws + META_OFF);
  int*   offs      = counts + 16;
  int*   cursors   = counts + 32;

  hipMemsetAsync(counts, 0, 192, stream);
  hipMemsetAsync(out, 0, (size_t)TOKENS * DMODEL * sizeof(float), stream);

  convert_x_kernel<<<TOKENS * DMODEL / 4 / 256, 256, 0, stream>>>(x, xb);

  transpose_cvt64_kernel<<<dim3(HDIM / 64, DMODEL / 64, NEXP), 256, 0, stream>>>(rw1, w1t, DMODEL, HDIM);
  transpose_cvt64_kernel<<<dim3(HDIM / 64, DMODEL / 64, NSH), 256, 0, stream>>>(
      sw1, w1t + (size_t)NEXP * HDIM * DMODEL, DMODEL, HDIM);
  transpose_cvt64_kernel<<<dim3(HDIM / 64, DMODEL / 64, NEXP), 256, 0, stream>>>(rw2, w2t, DMODEL, HDIM);
  transpose_cvt64_kernel<<<dim3(HDIM / 64, DMODEL / 64, NSH), 256, 0, stream>>>(
      sw2, w2t + (size_t)NEXP * HDIM * DMODEL, DMODEL, HDIM);
  transpose_cvt64_kernel<<<dim3(DMODEL / 64, HDIM / 64, NEXP), 256, 0, stream>>>(rw3, w3t, HDIM, DMODEL);
  transpose_cvt64_kernel<<<dim3(DMODEL / 64, HDIM / 64, NSH), 256, 0, stream>>>(
      sw3, w3t + (size_t)NEXP * DMODEL * HDIM, HDIM, DMODEL);

  gate_kernel<<<TOKENS, 64, 0, stream>>>(x, gate_w, gate_b, topk_idx, topk_w, counts);
  offs_kernel<<<1, 64, 0, stream>>>(counts, offs);
  scatter_kernel<<<TOKENS / 256, 256, 0, stream>>>(topk_idx, topk_w, offs, cursors,
                                                   row_token, row_coef);

  gemm1_kernel<<<dim3(TOKENS / 256, HDIM / 128, NGRP), 512, 0, stream>>>(
      xb, w1t, w2t, rb1, sb1, rb2, sb2, offs, row_token, glu);
  gemm2_kernel<<<dim3(TOKENS / 256, DMODEL / 256, NGRP), 512, 0, stream>>>(
      glu, w3t, rb3, sb3, offs, row_token, row_coef, out);
}

// Round 5
// 1330.669 us; speedup vs baseline: 1.4009x; 1.4009x over previous
//
#include <hip/hip_runtime.h>
#include <math.h>

#define TOKENS   8192
#define DMODEL   1024
#define HDIM     2048
#define NEXP     8
#define NSH      2
#define NGRP     10
#define R_ROUTED 16384
#define R_TOTAL  32768

typedef float  f32x4  __attribute__((ext_vector_type(4)));
typedef __bf16 bf16x8 __attribute__((ext_vector_type(8)));
typedef unsigned short u16x8 __attribute__((ext_vector_type(8)));

typedef __attribute__((address_space(1))) const void as1_void;
typedef __attribute__((address_space(3))) void as3_void;
#define GLOAD16(g, l) __builtin_amdgcn_global_load_lds((as1_void*)(g), (as3_void*)(l), 16, 0, 0)

__device__ __forceinline__ unsigned short f2bf(float f) {
  unsigned int u = __float_as_uint(f);
  u += 0x7fffu + ((u >> 16) & 1u);
  return (unsigned short)(u >> 16);
}

// swizzle for 32-elem (64B) LDS rows: involution in chunk index
__device__ __forceinline__ int swz32(int row) { return (row & 3) ^ ((row >> 2) & 1); }

// ---------------- conversion kernels ----------------

__global__ __launch_bounds__(256) void convert_x_kernel(const float* __restrict__ x,
                                                        unsigned short* __restrict__ xb) {
  int i = blockIdx.x * blockDim.x + threadIdx.x;
  const float4 v = reinterpret_cast<const float4*>(x)[i];
  ushort4 o;
  o.x = f2bf(v.x); o.y = f2bf(v.y); o.z = f2bf(v.z); o.w = f2bf(v.w);
  reinterpret_cast<ushort4*>(xb)[i] = o;
}

// transpose fp32 (R x C) -> bf16 (C x R), 64x64 tiles, vectorized both sides
__global__ __launch_bounds__(256) void transpose_cvt64_kernel(const float* __restrict__ src,
                                                              unsigned short* __restrict__ dst,
                                                              int R, int C) {
  __shared__ float tile[64][65];
  const size_t mat = blockIdx.z;
  src += mat * (size_t)R * C;
  dst += mat * (size_t)R * C;
  const int c0 = blockIdx.x * 64, r0 = blockIdx.y * 64;
  const int tid = threadIdx.x;
  const int tx = tid & 15, ty = tid >> 4;     // 16 x 16
  #pragma unroll
  for (int rr = 0; rr < 4; ++rr) {
    const int row = ty + rr * 16;
    const float4 v = *reinterpret_cast<const float4*>(&src[(size_t)(r0 + row) * C + c0 + tx * 4]);
    tile[row][tx * 4 + 0] = v.x;
    tile[row][tx * 4 + 1] = v.y;
    tile[row][tx * 4 + 2] = v.z;
    tile[row][tx * 4 + 3] = v.w;
  }
  __syncthreads();
  const int oc = tid >> 2, og = tid & 3;      // col 0..63, r-quarter 0..3
  u16x8 u0, u1;
  #pragma unroll
  for (int e = 0; e < 8; ++e) u0[e] = f2bf(tile[og * 16 + e][oc]);
  #pragma unroll
  for (int e = 0; e < 8; ++e) u1[e] = f2bf(tile[og * 16 + 8 + e][oc]);
  unsigned short* dp = &dst[(size_t)(c0 + oc) * R + r0 + og * 16];
  *reinterpret_cast<u16x8*>(dp) = u0;
  *reinterpret_cast<u16x8*>(dp + 8) = u1;
}

// ---------------- gating / routing ----------------

__global__ __launch_bounds__(64) void gate_kernel(const float* __restrict__ x,
                                                  const float* __restrict__ gw,
                                                  const float* __restrict__ gb,
                                                  int* __restrict__ topk_idx,
                                                  float* __restrict__ topk_w,
                                                  int* __restrict__ counts) {
  const int t = blockIdx.x;
  const int lane = threadIdx.x;
  const float* xr = x + (size_t)t * DMODEL;
  float acc[NEXP];
  #pragma unroll
  for (int e = 0; e < NEXP; ++e) acc[e] = 0.f;
  for (int d = lane; d < DMODEL; d += 64) {
    const float xv = xr[d];
    const float* g = gw + (size_t)d * NEXP;
    #pragma unroll
    for (int e = 0; e < NEXP; ++e) acc[e] += xv * g[e];
  }
  #pragma unroll
  for (int e = 0; e < NEXP; ++e) {
    float v = acc[e];
    v += __shfl_down(v, 32); v += __shfl_down(v, 16); v += __shfl_down(v, 8);
    v += __shfl_down(v, 4);  v += __shfl_down(v, 2);  v += __shfl_down(v, 1);
    acc[e] = v;
  }
  if (lane == 0) {
    float p[NEXP];
    float mx = -1e30f;
    #pragma unroll
    for (int e = 0; e < NEXP; ++e) { acc[e] += gb[e]; mx = fmaxf(mx, acc[e]); }
    float s = 0.f;
    #pragma unroll
    for (int e = 0; e < NEXP; ++e) { p[e] = expf(acc[e] - mx); s += p[e]; }
    const float inv = 1.f / s;
    #pragma unroll
    for (int e = 0; e < NEXP; ++e) p[e] *= inv;
    int i1 = 0; float v1 = p[0];
    #pragma unroll
    for (int e = 1; e < NEXP; ++e) if (p[e] > v1) { v1 = p[e]; i1 = e; }
    int i2 = -1; float v2 = -1e30f;
    #pragma unroll
    for (int e = 0; e < NEXP; ++e) if (e != i1 && p[e] > v2) { v2 = p[e]; i2 = e; }
    topk_idx[t * 2 + 0] = i1; topk_w[t * 2 + 0] = v1;
    topk_idx[t * 2 + 1] = i2; topk_w[t * 2 + 1] = v2;
    atomicAdd(&counts[i1], 1);
    atomicAdd(&counts[i2], 1);
  }
}

__global__ void offs_kernel(const int* __restrict__ counts, int* __restrict__ offs) {
  if (threadIdx.x == 0 && blockIdx.x == 0) {
    int cum = 0;
    for (int e = 0; e < NEXP; ++e) { offs[e] = cum; cum += counts[e]; }
    offs[8] = R_ROUTED;
    offs[9] = R_ROUTED + TOKENS;
    offs[10] = R_TOTAL;
  }
}

__global__ __launch_bounds__(256) void scatter_kernel(const int* __restrict__ topk_idx,
                                                      const float* __restrict__ topk_w,
                                                      const int* __restrict__ offs,
                                                      int* __restrict__ cursors,
                                                      int* __restrict__ row_token,
                                                      float* __restrict__ row_coef) {
  const int t = blockIdx.x * blockDim.x + threadIdx.x;
  if (t >= TOKENS) return;
  #pragma unroll
  for (int k = 0; k < 2; ++k) {
    const int e = topk_idx[t * 2 + k];
    const int pos = atomicAdd(&cursors[e], 1);
    const int r = offs[e] + pos;
    row_token[r] = t;
    row_coef[r] = topk_w[t * 2 + k];
  }
  row_token[R_ROUTED + t] = t;          row_coef[R_ROUTED + t] = 0.5f;
  row_token[R_ROUTED + TOKENS + t] = t; row_coef[R_ROUTED + TOKENS + t] = 0.5f;
}

// ---- grouped GEMM 1 (BK=32, dbuf, stage-early, 1 barrier/K-tile) ----
// glu = silu(X W1 + b1) * (X W2 + b2).  128x128 tile, 256 thr (4 waves, 2Mx2N),
// LDS 48 KiB -> ~3 blocks/CU.  Swizzle: slot(row,j) holds chunk j^swz32(row).

__global__ __launch_bounds__(256, 2) void gemm1_kernel(
    const unsigned short* __restrict__ xb,
    const unsigned short* __restrict__ w1t,
    const unsigned short* __restrict__ w2t,
    const float* __restrict__ rb1, const float* __restrict__ sb1,
    const float* __restrict__ rb2, const float* __restrict__ sb2,
    const int* __restrict__ offs,
    const int* __restrict__ row_token,
    unsigned short* __restrict__ glu) {
  const int g = blockIdx.z;
  const int off_g = offs[g];
  const int n_g = offs[g + 1] - off_g;
  const int m0 = blockIdx.x * 128;
  if (m0 >= n_g) return;
  const int n0 = blockIdx.y * 128;

  __shared__ __align__(16) unsigned short Abuf[2][128 * 32];
  __shared__ __align__(16) unsigned short B1buf[2][128 * 32];
  __shared__ __align__(16) unsigned short B2buf[2][128 * 32];

  const int tid = threadIdx.x;
  const int lane = tid & 63;
  const int wid = tid >> 6;
  const int wm = wid >> 1, wn = wid & 1;
  const int l15 = lane & 15, kq = lane >> 4;

  const unsigned short* w1g = w1t + (size_t)g * HDIM * DMODEL;
  const unsigned short* w2g = w2t + (size_t)g * HDIM * DMODEL;

  // staging precompute: chunk = r*256+tid; row=chunk>>2; j=chunk&3; q=j^swz32(row)
  const unsigned short* srcA[2]; const unsigned short* srcB1[2];
  const unsigned short* srcB2[2]; int dst[2];
  #pragma unroll
  for (int r = 0; r < 2; ++r) {
    const int chunk = r * 256 + tid;
    const int row = chunk >> 2, j = chunk & 3;
    const int q = j ^ swz32(row);
    int ar = m0 + row; if (ar > n_g - 1) ar = n_g - 1;
    srcA[r]  = xb + (size_t)row_token[off_g + ar] * DMODEL + q * 8;
    srcB1[r] = w1g + (size_t)(n0 + row) * DMODEL + q * 8;
    srcB2[r] = w2g + (size_t)(n0 + row) * DMODEL + q * 8;
    dst[r] = (r * 256 + (tid & ~63)) * 8;   // elems (chunk*8)
  }

  f32x4 acc1[4][4], acc2[4][4];
  const f32x4 zero = {0.f, 0.f, 0.f, 0.f};
  #pragma unroll
  for (int i = 0; i < 4; ++i)
    #pragma unroll
    for (int j = 0; j < 4; ++j) { acc1[i][j] = zero; acc2[i][j] = zero; }

  auto stage = [&](int cur, int k0) {
    #pragma unroll
    for (int r = 0; r < 2; ++r) {
      GLOAD16(srcA[r]  + k0, &Abuf[cur][dst[r]]);
      GLOAD16(srcB1[r] + k0, &B1buf[cur][dst[r]]);
      GLOAD16(srcB2[r] + k0, &B2buf[cur][dst[r]]);
    }
  };

  stage(0, 0);
  __syncthreads();

  #define NT1 (DMODEL / 32)
  for (int kt = 0; kt < NT1; ++kt) {
    const int cur = kt & 1;
    if (kt + 1 < NT1) stage(cur ^ 1, (kt + 1) * 32);
    bf16x8 a[4], p[4], q2[4];
    #pragma unroll
    for (int mi = 0; mi < 4; ++mi) {
      const int row = wm * 64 + mi * 16 + l15;
      a[mi] = *reinterpret_cast<const bf16x8*>(&Abuf[cur][row * 32 + ((kq ^ swz32(row)) << 3)]);
    }
    #pragma unroll
    for (int ni = 0; ni < 4; ++ni) {
      const int row = wn * 64 + ni * 16 + l15;
      const int ko = (kq ^ swz32(row)) << 3;
      p[ni]  = *reinterpret_cast<const bf16x8*>(&B1buf[cur][row * 32 + ko]);
      q2[ni] = *reinterpret_cast<const bf16x8*>(&B2buf[cur][row * 32 + ko]);
    }
    #pragma unroll
    for (int mi = 0; mi < 4; ++mi)
      #pragma unroll
      for (int ni = 0; ni < 4; ++ni) {
        acc1[mi][ni] = __builtin_amdgcn_mfma_f32_16x16x32_bf16(a[mi], p[ni],  acc1[mi][ni], 0, 0, 0);
        acc2[mi][ni] = __builtin_amdgcn_mfma_f32_16x16x32_bf16(a[mi], q2[ni], acc2[mi][ni], 0, 0, 0);
      }
    __syncthreads();
  }

  const float* b1p = (g < NEXP) ? (rb1 + (size_t)g * HDIM) : (sb1 + (size_t)(g - NEXP) * HDIM);
  const float* b2p = (g < NEXP) ? (rb2 + (size_t)g * HDIM) : (sb2 + (size_t)(g - NEXP) * HDIM);

  #pragma unroll
  for (int mi = 0; mi < 4; ++mi) {
    #pragma unroll
    for (int r = 0; r < 4; ++r) {
      const int m = m0 + wm * 64 + mi * 16 + kq * 4 + r;
      if (m < n_g) {
        #pragma unroll
        for (int ni = 0; ni < 4; ++ni) {
          const int n = n0 + wn * 64 + ni * 16 + l15;
          const float x1 = acc1[mi][ni][r] + b1p[n];
          const float x2 = acc2[mi][ni][r] + b2p[n];
          glu[(size_t)(off_g + m) * HDIM + n] = f2bf((x1 / (1.f + expf(-x1))) * x2);
        }
      }
    }
  }
}

// ---- grouped GEMM 2 (BK=32, dbuf, stage-early, 1 barrier/K-tile) ----
// out += coef * (glu W3 + b3).  128x128 tile, 256 thr, LDS 32 KiB -> 4 blocks/CU.

__global__ __launch_bounds__(256, 2) void gemm2_kernel(
    const unsigned short* __restrict__ glu,
    const unsigned short* __restrict__ w3t,
    const float* __restrict__ rb3, const float* __restrict__ sb3,
    const int* __restrict__ offs,
    const int* __restrict__ row_token,
    const float* __restrict__ row_coef,
    float* __restrict__ out) {
  const int g = blockIdx.z;
  const int off_g = offs[g];
  const int n_g = offs[g + 1] - off_g;
  const int m0 = blockIdx.x * 128;
  if (m0 >= n_g) return;
  const int n0 = blockIdx.y * 128;

  __shared__ __align__(16) unsigned short Abuf[2][128 * 32];
  __shared__ __align__(16) unsigned short Bbuf[2][128 * 32];

  const int tid = threadIdx.x;
  const int lane = tid & 63;
  const int wid = tid >> 6;
  const int wm = wid >> 1, wn = wid & 1;
  const int l15 = lane & 15, kq = lane >> 4;

  const unsigned short* w3g = w3t + (size_t)g * DMODEL * HDIM;

  const unsigned short* srcA[2]; const unsigned short* srcB[2]; int dst[2];
  #pragma unroll
  for (int r = 0; r < 2; ++r) {
    const int chunk = r * 256 + tid;
    const int row = chunk >> 2, j = chunk & 3;
    const int q = j ^ swz32(row);
    int ar = m0 + row; if (ar > n_g - 1) ar = n_g - 1;
    srcA[r] = glu + (size_t)(off_g + ar) * HDIM + q * 8;
    srcB[r] = w3g + (size_t)(n0 + row) * HDIM + q * 8;
    dst[r] = (r * 256 + (tid & ~63)) * 8;
  }

  f32x4 acc[4][4];
  const f32x4 zero = {0.f, 0.f, 0.f, 0.f};
  #pragma unroll
  for (int i = 0; i < 4; ++i)
    #pragma unroll
    for (int j = 0; j < 4; ++j) acc[i][j] = zero;

  auto stage = [&](int cur, int k0) {
    #pragma unroll
    for (int r = 0; r < 2; ++r) {
      GLOAD16(srcA[r] + k0, &Abuf[cur][dst[r]]);
      GLOAD16(srcB[r] + k0, &Bbuf[cur][dst[r]]);
    }
  };

  stage(0, 0);
  __syncthreads();

  #define NT2 (HDIM / 32)
  for (int kt = 0; kt < NT2; ++kt) {
    const int cur = kt & 1;
    if (kt + 1 < NT2) stage(cur ^ 1, (kt + 1) * 32);
    bf16x8 a[4], b[4];
    #pragma unroll
    for (int mi = 0; mi < 4; ++mi) {
      const int row = wm * 64 + mi * 16 + l15;
      a[mi] = *reinterpret_cast<const bf16x8*>(&Abuf[cur][row * 32 + ((kq ^ swz32(row)) << 3)]);
    }
    #pragma unroll
    for (int ni = 0; ni < 4; ++ni) {
      const int row = wn * 64 + ni * 16 + l15;
      b[ni] = *reinterpret_cast<const bf16x8*>(&Bbuf[cur][row * 32 + ((kq ^ swz32(row)) << 3)]);
    }
    #pragma unroll
    for (int mi = 0; mi < 4; ++mi)
      #pragma unroll
      for (int ni = 0; ni < 4; ++ni)
        acc[mi][ni] = __builtin_amdgcn_mfma_f32_16x16x32_bf16(a[mi], b[ni], acc[mi][ni], 0, 0, 0);
    __syncthreads();
  }

  const float* b3p = (g < NEXP) ? (rb3 + (size_t)g * DMODEL) : (sb3 + (size_t)(g - NEXP) * DMODEL);

  #pragma unroll
  for (int mi = 0; mi < 4; ++mi) {
    #pragma unroll
    for (int r = 0; r < 4; ++r) {
      const int m = m0 + wm * 64 + mi * 16 + kq * 4 + r;
      if (m < n_g) {
        const int t = row_token[off_g + m];
        const float cf = row_coef[off_g + m];
        float* orow = out + (size_t)t * DMODEL;
        #pragma unroll
        for (int ni = 0; ni < 4; ++ni) {
          const int n = n0 + wn * 64 + ni * 16 + l15;
          atomicAdd(&orow[n], (acc[mi][ni][r] + b3p[n]) * cf);
        }
      }
    }
  }
}

// ---------------- launch ----------------

extern "C" void kernel_launch(void* const* d_in, const int* in_sizes, int n_in,
                              void* d_out, int out_size, void* d_ws, size_t ws_size,
                              hipStream_t stream) {
  const float* x      = (const float*)d_in[0];
  const float* gate_w = (const float*)d_in[1];
  const float* gate_b = (const float*)d_in[2];
  const float* rw1    = (const float*)d_in[3];
  const float* rb1    = (const float*)d_in[4];
  const float* rw2    = (const float*)d_in[5];
  const float* rb2    = (const float*)d_in[6];
  const float* rw3    = (const float*)d_in[7];
  const float* rb3    = (const float*)d_in[8];
  const float* sw1    = (const float*)d_in[9];
  const float* sb1    = (const float*)d_in[10];
  const float* sw2    = (const float*)d_in[11];
  const float* sb2    = (const float*)d_in[12];
  const float* sw3    = (const float*)d_in[13];
  const float* sb3    = (const float*)d_in[14];
  float* out = (float*)d_out;

  // workspace layout
  const size_t XB_OFF   = 0;
  const size_t W1T_OFF  = XB_OFF  + (size_t)TOKENS * DMODEL * 2;
  const size_t W2T_OFF  = W1T_OFF + (size_t)NGRP * HDIM * DMODEL * 2;
  const size_t W3T_OFF  = W2T_OFF + (size_t)NGRP * HDIM * DMODEL * 2;
  const size_t GLU_OFF  = W3T_OFF + (size_t)NGRP * DMODEL * HDIM * 2;
  const size_t RTOK_OFF = GLU_OFF + (size_t)R_TOTAL * HDIM * 2;
  const size_t RCOE_OFF = RTOK_OFF + (size_t)R_TOTAL * 4;
  const size_t TKI_OFF  = RCOE_OFF + (size_t)R_TOTAL * 4;
  const size_t TKW_OFF  = TKI_OFF + (size_t)TOKENS * 2 * 4;
  const size_t META_OFF = TKW_OFF + (size_t)TOKENS * 2 * 4;
  const size_t NEED     = META_OFF + 256;
  if (ws_size < NEED) return;

  char* ws = (char*)d_ws;
  unsigned short* xb   = (unsigned short*)(ws + XB_OFF);
  unsigned short* w1t  = (unsigned short*)(ws + W1T_OFF);
  unsigned short* w2t  = (unsigned short*)(ws + W2T_OFF);
  unsigned short* w3t  = (unsigned short*)(ws + W3T_OFF);
  unsigned short* glu  = (unsigned short*)(ws + GLU_OFF);
  int*   row_token = (int*)(ws + RTOK_OFF);
  float* row_coef  = (float*)(ws + RCOE_OFF);
  int*   topk_idx  = (int*)(ws + TKI_OFF);
  float* topk_w    = (float*)(ws + TKW_OFF);
  int*   counts    = (int*)(ws + META_OFF);
  int*   offs      = counts + 16;
  int*   cursors   = counts + 32;

  hipMemsetAsync(counts, 0, 192, stream);
  hipMemsetAsync(out, 0, (size_t)TOKENS * DMODEL * sizeof(float), stream);

  convert_x_kernel<<<TOKENS * DMODEL / 4 / 256, 256, 0, stream>>>(x, xb);

  transpose_cvt64_kernel<<<dim3(HDIM / 64, DMODEL / 64, NEXP), 256, 0, stream>>>(rw1, w1t, DMODEL, HDIM);
  transpose_cvt64_kernel<<<dim3(HDIM / 64, DMODEL / 64, NSH), 256, 0, stream>>>(
      sw1, w1t + (size_t)NEXP * HDIM * DMODEL, DMODEL, HDIM);
  transpose_cvt64_kernel<<<dim3(HDIM / 64, DMODEL / 64, NEXP), 256, 0, stream>>>(rw2, w2t, DMODEL, HDIM);
  transpose_cvt64_kernel<<<dim3(HDIM / 64, DMODEL / 64, NSH), 256, 0, stream>>>(
      sw2, w2t + (size_t)NEXP * HDIM * DMODEL, DMODEL, HDIM);
  transpose_cvt64_kernel<<<dim3(DMODEL / 64, HDIM / 64, NEXP), 256, 0, stream>>>(rw3, w3t, HDIM, DMODEL);
  transpose_cvt64_kernel<<<dim3(DMODEL / 64, HDIM / 64, NSH), 256, 0, stream>>>(
      sw3, w3t + (size_t)NEXP * DMODEL * HDIM, HDIM, DMODEL);

  gate_kernel<<<TOKENS, 64, 0, stream>>>(x, gate_w, gate_b, topk_idx, topk_w, counts);
  offs_kernel<<<1, 64, 0, stream>>>(counts, offs);
  scatter_kernel<<<TOKENS / 256, 256, 0, stream>>>(topk_idx, topk_w, offs, cursors,
                                                   row_token, row_coef);

  gemm1_kernel<<<dim3(TOKENS / 128, HDIM / 128, NGRP), 256, 0, stream>>>(
      xb, w1t, w2t, rb1, sb1, rb2, sb2, offs, row_token, glu);
  gemm2_kernel<<<dim3(TOKENS / 128, DMODEL / 128, NGRP), 256, 0, stream>>>(
      glu, w3t, rb3, sb3, offs, row_token, row_coef, out);
}

// Round 7
// 1039.726 us; speedup vs baseline: 1.7929x; 1.2798x over previous
//
#include <hip/hip_runtime.h>
#include <math.h>

#define TOKENS   8192
#define DMODEL   1024
#define HDIM     2048
#define NEXP     8
#define NSH      2
#define NGRP     10
#define R_ROUTED 16384
#define R_TOTAL  32768

typedef float  f32x4  __attribute__((ext_vector_type(4)));
typedef __bf16 bf16x8 __attribute__((ext_vector_type(8)));
typedef unsigned short u16x8 __attribute__((ext_vector_type(8)));

typedef __attribute__((address_space(1))) const void as1_void;
typedef __attribute__((address_space(3))) void as3_void;
#define GLOAD16(g, l) __builtin_amdgcn_global_load_lds((as1_void*)(g), (as3_void*)(l), 16, 0, 0)

__device__ __forceinline__ unsigned short f2bf(float f) {
  unsigned int u = __float_as_uint(f);
  u += 0x7fffu + ((u >> 16) & 1u);
  return (unsigned short)(u >> 16);
}
__device__ __forceinline__ float bf2f(unsigned short u) {
  return __uint_as_float(((unsigned int)u) << 16);
}

// ---------------- conversion kernels ----------------

__global__ __launch_bounds__(256) void convert_x_kernel(const float* __restrict__ x,
                                                        unsigned short* __restrict__ xb) {
  int i = blockIdx.x * blockDim.x + threadIdx.x;
  const float4 v = reinterpret_cast<const float4*>(x)[i];
  ushort4 o;
  o.x = f2bf(v.x); o.y = f2bf(v.y); o.z = f2bf(v.z); o.w = f2bf(v.w);
  reinterpret_cast<ushort4*>(xb)[i] = o;
}

// transpose fp32 (R x C) -> bf16 (C x R), 64x64 tiles, vectorized both sides
__global__ __launch_bounds__(256) void transpose_cvt64_kernel(const float* __restrict__ src,
                                                              unsigned short* __restrict__ dst,
                                                              int R, int C) {
  __shared__ float tile[64][65];
  const size_t mat = blockIdx.z;
  src += mat * (size_t)R * C;
  dst += mat * (size_t)R * C;
  const int c0 = blockIdx.x * 64, r0 = blockIdx.y * 64;
  const int tid = threadIdx.x;
  const int tx = tid & 15, ty = tid >> 4;     // 16 x 16
  #pragma unroll
  for (int rr = 0; rr < 4; ++rr) {
    const int row = ty + rr * 16;
    const float4 v = *reinterpret_cast<const float4*>(&src[(size_t)(r0 + row) * C + c0 + tx * 4]);
    tile[row][tx * 4 + 0] = v.x;
    tile[row][tx * 4 + 1] = v.y;
    tile[row][tx * 4 + 2] = v.z;
    tile[row][tx * 4 + 3] = v.w;
  }
  __syncthreads();
  const int oc = tid >> 2, og = tid & 3;      // col 0..63, r-quarter 0..3
  u16x8 u0, u1;
  #pragma unroll
  for (int e = 0; e < 8; ++e) u0[e] = f2bf(tile[og * 16 + e][oc]);
  #pragma unroll
  for (int e = 0; e < 8; ++e) u1[e] = f2bf(tile[og * 16 + 8 + e][oc]);
  unsigned short* dp = &dst[(size_t)(c0 + oc) * R + r0 + og * 16];
  *reinterpret_cast<u16x8*>(dp) = u0;
  *reinterpret_cast<u16x8*>(dp + 8) = u1;
}

// ---------------- gating / routing ----------------

__global__ __launch_bounds__(64) void gate_kernel(const float* __restrict__ x,
                                                  const float* __restrict__ gw,
                                                  const float* __restrict__ gb,
                                                  int* __restrict__ topk_idx,
                                                  float* __restrict__ topk_w,
                                                  int* __restrict__ counts) {
  const int t = blockIdx.x;
  const int lane = threadIdx.x;
  const float* xr = x + (size_t)t * DMODEL;
  float acc[NEXP];
  #pragma unroll
  for (int e = 0; e < NEXP; ++e) acc[e] = 0.f;
  for (int d = lane; d < DMODEL; d += 64) {
    const float xv = xr[d];
    const float* g = gw + (size_t)d * NEXP;
    #pragma unroll
    for (int e = 0; e < NEXP; ++e) acc[e] += xv * g[e];
  }
  #pragma unroll
  for (int e = 0; e < NEXP; ++e) {
    float v = acc[e];
    v += __shfl_down(v, 32); v += __shfl_down(v, 16); v += __shfl_down(v, 8);
    v += __shfl_down(v, 4);  v += __shfl_down(v, 2);  v += __shfl_down(v, 1);
    acc[e] = v;
  }
  if (lane == 0) {
    float p[NEXP];
    float mx = -1e30f;
    #pragma unroll
    for (int e = 0; e < NEXP; ++e) { acc[e] += gb[e]; mx = fmaxf(mx, acc[e]); }
    float s = 0.f;
    #pragma unroll
    for (int e = 0; e < NEXP; ++e) { p[e] = expf(acc[e] - mx); s += p[e]; }
    const float inv = 1.f / s;
    #pragma unroll
    for (int e = 0; e < NEXP; ++e) p[e] *= inv;
    int i1 = 0; float v1 = p[0];
    #pragma unroll
    for (int e = 1; e < NEXP; ++e) if (p[e] > v1) { v1 = p[e]; i1 = e; }
    int i2 = -1; float v2 = -1e30f;
    #pragma unroll
    for (int e = 0; e < NEXP; ++e) if (e != i1 && p[e] > v2) { v2 = p[e]; i2 = e; }
    topk_idx[t * 2 + 0] = i1; topk_w[t * 2 + 0] = v1;
    topk_idx[t * 2 + 1] = i2; topk_w[t * 2 + 1] = v2;
    atomicAdd(&counts[i1], 1);
    atomicAdd(&counts[i2], 1);
  }
}

__global__ void offs_kernel(const int* __restrict__ counts, int* __restrict__ offs) {
  if (threadIdx.x == 0 && blockIdx.x == 0) {
    int cum = 0;
    for (int e = 0; e < NEXP; ++e) { offs[e] = cum; cum += counts[e]; }
    offs[8] = R_ROUTED;
    offs[9] = R_ROUTED + TOKENS;
    offs[10] = R_TOTAL;
  }
}

__global__ __launch_bounds__(256) void scatter_kernel(const int* __restrict__ topk_idx,
                                                      const int* __restrict__ offs,
                                                      int* __restrict__ cursors,
                                                      int* __restrict__ row_token,
                                                      int* __restrict__ tok_rows) {
  const int t = blockIdx.x * blockDim.x + threadIdx.x;
  if (t >= TOKENS) return;
  #pragma unroll
  for (int k = 0; k < 2; ++k) {
    const int e = topk_idx[t * 2 + k];
    const int pos = atomicAdd(&cursors[e], 1);
    const int r = offs[e] + pos;
    row_token[r] = t;
    tok_rows[t * 2 + k] = r;
  }
  row_token[R_ROUTED + t] = t;
  row_token[R_ROUTED + TOKENS + t] = t;
}

// ---- grouped GEMM 1: glu = silu(X W1 + b1) * (X W2 + b2) ----
// Tile 128m x 64n (dual B), BK=64, 256 thr (4 waves, 2M x 2N), per-wave 64x32 dual.
// acc = 16 f32x4 = 64 AGPR -> ~160 unified regs -> 3 blocks/CU.
// Single-buffer LDS (32.5 KiB), R2's verified schedule + 8-chunk XOR swizzle.

__global__ __launch_bounds__(256, 3) void gemm1_kernel(
    const unsigned short* __restrict__ xb,
    const unsigned short* __restrict__ w1t,
    const unsigned short* __restrict__ w2t,
    const float* __restrict__ rb1, const float* __restrict__ sb1,
    const float* __restrict__ rb2, const float* __restrict__ sb2,
    const int* __restrict__ offs,
    const int* __restrict__ row_token,
    unsigned short* __restrict__ glu) {
  const int g = blockIdx.z;
  const int off_g = offs[g];
  const int n_g = offs[g + 1] - off_g;
  const int m0 = blockIdx.x * 128;
  if (m0 >= n_g) return;
  const int n0 = blockIdx.y * 64;

  __shared__ __align__(16) unsigned short Abuf[128 * 64];
  __shared__ __align__(16) unsigned short B1buf[64 * 64];
  __shared__ __align__(16) unsigned short B2buf[64 * 64];

  const int tid = threadIdx.x;
  const int lane = tid & 63;
  const int wid = tid >> 6;
  const int wm = wid >> 1, wn = wid & 1;
  const int l15 = lane & 15, kq = lane >> 4;

  const unsigned short* w1g = w1t + (size_t)g * HDIM * DMODEL;
  const unsigned short* w2g = w2t + (size_t)g * HDIM * DMODEL;

  const unsigned short* srcA[4]; int dA[4];
  #pragma unroll
  for (int r = 0; r < 4; ++r) {
    const int chunk = r * 256 + tid, row = chunk >> 3, j = chunk & 7;
    int ar = m0 + row; if (ar > n_g - 1) ar = n_g - 1;
    srcA[r] = xb + (size_t)row_token[off_g + ar] * DMODEL + ((j ^ (row & 7)) << 3);
    dA[r] = (r * 256 + (tid & ~63)) << 3;
  }
  const unsigned short* srcB1[2]; const unsigned short* srcB2[2]; int dB[2];
  #pragma unroll
  for (int r = 0; r < 2; ++r) {
    const int chunk = r * 256 + tid, row = chunk >> 3, j = chunk & 7;
    const size_t o = (size_t)(n0 + row) * DMODEL + ((j ^ (row & 7)) << 3);
    srcB1[r] = w1g + o; srcB2[r] = w2g + o;
    dB[r] = (r * 256 + (tid & ~63)) << 3;
  }

  f32x4 acc1[4][2], acc2[4][2];
  const f32x4 zero = {0.f, 0.f, 0.f, 0.f};
  #pragma unroll
  for (int i = 0; i < 4; ++i)
    #pragma unroll
    for (int j = 0; j < 2; ++j) { acc1[i][j] = zero; acc2[i][j] = zero; }

  for (int k0 = 0; k0 < DMODEL; k0 += 64) {
    __syncthreads();
    #pragma unroll
    for (int r = 0; r < 4; ++r) GLOAD16(srcA[r] + k0, &Abuf[dA[r]]);
    #pragma unroll
    for (int r = 0; r < 2; ++r) {
      GLOAD16(srcB1[r] + k0, &B1buf[dB[r]]);
      GLOAD16(srcB2[r] + k0, &B2buf[dB[r]]);
    }
    __syncthreads();
    #pragma unroll
    for (int ks = 0; ks < 2; ++ks) {
      const int kc = ks * 4 + kq;
      bf16x8 a[4], p[2], q[2];
      #pragma unroll
      for (int mi = 0; mi < 4; ++mi) {
        const int row = wm * 64 + mi * 16 + l15;
        a[mi] = *reinterpret_cast<const bf16x8*>(&Abuf[row * 64 + ((kc ^ (row & 7)) << 3)]);
      }
      #pragma unroll
      for (int ni = 0; ni < 2; ++ni) {
        const int row = wn * 32 + ni * 16 + l15;
        const int ko = (kc ^ (row & 7)) << 3;
        p[ni] = *reinterpret_cast<const bf16x8*>(&B1buf[row * 64 + ko]);
        q[ni] = *reinterpret_cast<const bf16x8*>(&B2buf[row * 64 + ko]);
      }
      #pragma unroll
      for (int mi = 0; mi < 4; ++mi)
        #pragma unroll
        for (int ni = 0; ni < 2; ++ni) {
          acc1[mi][ni] = __builtin_amdgcn_mfma_f32_16x16x32_bf16(a[mi], p[ni], acc1[mi][ni], 0, 0, 0);
          acc2[mi][ni] = __builtin_amdgcn_mfma_f32_16x16x32_bf16(a[mi], q[ni], acc2[mi][ni], 0, 0, 0);
        }
    }
  }

  const float* b1p = (g < NEXP) ? (rb1 + (size_t)g * HDIM) : (sb1 + (size_t)(g - NEXP) * HDIM);
  const float* b2p = (g < NEXP) ? (rb2 + (size_t)g * HDIM) : (sb2 + (size_t)(g - NEXP) * HDIM);

  #pragma unroll
  for (int mi = 0; mi < 4; ++mi) {
    #pragma unroll
    for (int r = 0; r < 4; ++r) {
      const int m = m0 + wm * 64 + mi * 16 + kq * 4 + r;
      if (m < n_g) {
        #pragma unroll
        for (int ni = 0; ni < 2; ++ni) {
          const int n = n0 + wn * 32 + ni * 16 + l15;
          const float x1 = acc1[mi][ni][r] + b1p[n];
          const float x2 = acc2[mi][ni][r] + b2p[n];
          glu[(size_t)(off_g + m) * HDIM + n] = f2bf((x1 / (1.f + expf(-x1))) * x2);
        }
      }
    }
  }
}

// ---- grouped GEMM 2: y = (glu W3 + b3) as bf16, NO atomics ----
// 128x128 tile, BK=64, 256 thr (4 waves 2Mx2N), ~164 regs -> 3 blocks/CU.

__global__ __launch_bounds__(256, 3) void gemm2_kernel(
    const unsigned short* __restrict__ glu,
    const unsigned short* __restrict__ w3t,
    const float* __restrict__ rb3, const float* __restrict__ sb3,
    const int* __restrict__ offs,
    unsigned short* __restrict__ y) {
  const int g = blockIdx.z;
  const int off_g = offs[g];
  const int n_g = offs[g + 1] - off_g;
  const int m0 = blockIdx.x * 128;
  if (m0 >= n_g) return;
  const int n0 = blockIdx.y * 128;

  __shared__ __align__(16) unsigned short Abuf[128 * 64];
  __shared__ __align__(16) unsigned short Bbuf[128 * 64];

  const int tid = threadIdx.x;
  const int lane = tid & 63;
  const int wid = tid >> 6;
  const int wm = wid >> 1, wn = wid & 1;
  const int l15 = lane & 15, kq = lane >> 4;

  const unsigned short* w3g = w3t + (size_t)g * DMODEL * HDIM;

  const unsigned short* srcA[4]; const unsigned short* srcB[4]; int dAB[4];
  #pragma unroll
  for (int r = 0; r < 4; ++r) {
    const int chunk = r * 256 + tid, row = chunk >> 3, j = chunk & 7;
    int ar = m0 + row; if (ar > n_g - 1) ar = n_g - 1;
    srcA[r] = glu + (size_t)(off_g + ar) * HDIM + ((j ^ (row & 7)) << 3);
    srcB[r] = w3g + (size_t)(n0 + row) * HDIM + ((j ^ (row & 7)) << 3);
    dAB[r] = (r * 256 + (tid & ~63)) << 3;
  }

  f32x4 acc[4][4];
  const f32x4 zero = {0.f, 0.f, 0.f, 0.f};
  #pragma unroll
  for (int i = 0; i < 4; ++i)
    #pragma unroll
    for (int j = 0; j < 4; ++j) acc[i][j] = zero;

  for (int k0 = 0; k0 < HDIM; k0 += 64) {
    __syncthreads();
    #pragma unroll
    for (int r = 0; r < 4; ++r) {
      GLOAD16(srcA[r] + k0, &Abuf[dAB[r]]);
      GLOAD16(srcB[r] + k0, &Bbuf[dAB[r]]);
    }
    __syncthreads();
    #pragma unroll
    for (int ks = 0; ks < 2; ++ks) {
      const int kc = ks * 4 + kq;
      bf16x8 a[4], b[4];
      #pragma unroll
      for (int mi = 0; mi < 4; ++mi) {
        const int row = wm * 64 + mi * 16 + l15;
        a[mi] = *reinterpret_cast<const bf16x8*>(&Abuf[row * 64 + ((kc ^ (row & 7)) << 3)]);
      }
      #pragma unroll
      for (int ni = 0; ni < 4; ++ni) {
        const int row = wn * 64 + ni * 16 + l15;
        b[ni] = *reinterpret_cast<const bf16x8*>(&Bbuf[row * 64 + ((kc ^ (row & 7)) << 3)]);
      }
      #pragma unroll
      for (int mi = 0; mi < 4; ++mi)
        #pragma unroll
        for (int ni = 0; ni < 4; ++ni)
          acc[mi][ni] = __builtin_amdgcn_mfma_f32_16x16x32_bf16(a[mi], b[ni], acc[mi][ni], 0, 0, 0);
    }
  }

  const float* b3p = (g < NEXP) ? (rb3 + (size_t)g * DMODEL) : (sb3 + (size_t)(g - NEXP) * DMODEL);

  #pragma unroll
  for (int mi = 0; mi < 4; ++mi) {
    #pragma unroll
    for (int r = 0; r < 4; ++r) {
      const int m = m0 + wm * 64 + mi * 16 + kq * 4 + r;
      if (m < n_g) {
        unsigned short* yrow = y + (size_t)(off_g + m) * DMODEL;
        #pragma unroll
        for (int ni = 0; ni < 4; ++ni) {
          const int n = n0 + wn * 64 + ni * 16 + l15;
          yrow[n] = f2bf(acc[mi][ni][r] + b3p[n]);
        }
      }
    }
  }
}

// ---- reduce: out[t] = w0*y[r0] + w1*y[r1] + 0.5*y[sh0] + 0.5*y[sh1] ----

__global__ __launch_bounds__(256) void reduce_kernel(const unsigned short* __restrict__ y,
                                                     const int* __restrict__ tok_rows,
                                                     const float* __restrict__ topk_w,
                                                     float* __restrict__ out) {
  const int t = blockIdx.x * 2 + (threadIdx.x >> 7);
  const int col = (threadIdx.x & 127) * 8;
  const int r0 = tok_rows[t * 2 + 0], r1 = tok_rows[t * 2 + 1];
  const float w0 = topk_w[t * 2 + 0], w1 = topk_w[t * 2 + 1];

  float o[8];
  #pragma unroll
  for (int e = 0; e < 8; ++e) o[e] = 0.f;
  auto addrow = [&](const unsigned short* p, float w) {
    const u16x8 v = *reinterpret_cast<const u16x8*>(p);
    #pragma unroll
    for (int e = 0; e < 8; ++e) o[e] += w * bf2f(v[e]);
  };
  addrow(y + (size_t)r0 * DMODEL + col, w0);
  addrow(y + (size_t)r1 * DMODEL + col, w1);
  addrow(y + (size_t)(R_ROUTED + t) * DMODEL + col, 0.5f);
  addrow(y + (size_t)(R_ROUTED + TOKENS + t) * DMODEL + col, 0.5f);

  float4* op = reinterpret_cast<float4*>(out + (size_t)t * DMODEL + col);
  op[0] = make_float4(o[0], o[1], o[2], o[3]);
  op[1] = make_float4(o[4], o[5], o[6], o[7]);
}

// ---------------- launch ----------------

extern "C" void kernel_launch(void* const* d_in, const int* in_sizes, int n_in,
                              void* d_out, int out_size, void* d_ws, size_t ws_size,
                              hipStream_t stream) {
  const float* x      = (const float*)d_in[0];
  const float* gate_w = (const float*)d_in[1];
  const float* gate_b = (const float*)d_in[2];
  const float* rw1    = (const float*)d_in[3];
  const float* rb1    = (const float*)d_in[4];
  const float* rw2    = (const float*)d_in[5];
  const float* rb2    = (const float*)d_in[6];
  const float* rw3    = (const float*)d_in[7];
  const float* rb3    = (const float*)d_in[8];
  const float* sw1    = (const float*)d_in[9];
  const float* sb1    = (const float*)d_in[10];
  const float* sw2    = (const float*)d_in[11];
  const float* sb2    = (const float*)d_in[12];
  const float* sw3    = (const float*)d_in[13];
  const float* sb3    = (const float*)d_in[14];
  float* out = (float*)d_out;

  // workspace layout.  NOTE: y ALIASES w1t/w2t (y 67.1MB < w1t+w2t 83.9MB):
  // stream order guarantees w1t/w2t are dead (gemm1 done) before gemm2 writes y.
  const size_t XB_OFF   = 0;
  const size_t W1T_OFF  = XB_OFF  + (size_t)TOKENS * DMODEL * 2;
  const size_t W2T_OFF  = W1T_OFF + (size_t)NGRP * HDIM * DMODEL * 2;
  const size_t W3T_OFF  = W2T_OFF + (size_t)NGRP * HDIM * DMODEL * 2;
  const size_t GLU_OFF  = W3T_OFF + (size_t)NGRP * DMODEL * HDIM * 2;
  const size_t Y_OFF    = W1T_OFF;                       // alias over w1t/w2t
  const size_t RTOK_OFF = GLU_OFF + (size_t)R_TOTAL * HDIM * 2;
  const size_t TKI_OFF  = RTOK_OFF + (size_t)R_TOTAL * 4;
  const size_t TKW_OFF  = TKI_OFF + (size_t)TOKENS * 2 * 4;
  const size_t TRW_OFF  = TKW_OFF + (size_t)TOKENS * 2 * 4;
  const size_t META_OFF = TRW_OFF + (size_t)TOKENS * 2 * 4;
  const size_t NEED     = META_OFF + 256;
  if (ws_size < NEED) return;

  char* ws = (char*)d_ws;
  unsigned short* xb   = (unsigned short*)(ws + XB_OFF);
  unsigned short* w1t  = (unsigned short*)(ws + W1T_OFF);
  unsigned short* w2t  = (unsigned short*)(ws + W2T_OFF);
  unsigned short* w3t  = (unsigned short*)(ws + W3T_OFF);
  unsigned short* glu  = (unsigned short*)(ws + GLU_OFF);
  unsigned short* yy   = (unsigned short*)(ws + Y_OFF);
  int*   row_token = (int*)(ws + RTOK_OFF);
  int*   topk_idx  = (int*)(ws + TKI_OFF);
  float* topk_w    = (float*)(ws + TKW_OFF);
  int*   tok_rows  = (int*)(ws + TRW_OFF);
  int*   counts    = (int*)(ws + META_OFF);
  int*   offs      = counts + 16;
  int*   cursors   = counts + 32;

  hipMemsetAsync(counts, 0, 192, stream);

  convert_x_kernel<<<TOKENS * DMODEL / 4 / 256, 256, 0, stream>>>(x, xb);

  transpose_cvt64_kernel<<<dim3(HDIM / 64, DMODEL / 64, NEXP), 256, 0, stream>>>(rw1, w1t, DMODEL, HDIM);
  transpose_cvt64_kernel<<<dim3(HDIM / 64, DMODEL / 64, NSH), 256, 0, stream>>>(
      sw1, w1t + (size_t)NEXP * HDIM * DMODEL, DMODEL, HDIM);
  transpose_cvt64_kernel<<<dim3(HDIM / 64, DMODEL / 64, NEXP), 256, 0, stream>>>(rw2, w2t, DMODEL, HDIM);
  transpose_cvt64_kernel<<<dim3(HDIM / 64, DMODEL / 64, NSH), 256, 0, stream>>>(
      sw2, w2t + (size_t)NEXP * HDIM * DMODEL, DMODEL, HDIM);
  transpose_cvt64_kernel<<<dim3(DMODEL / 64, HDIM / 64, NEXP), 256, 0, stream>>>(rw3, w3t, HDIM, DMODEL);
  transpose_cvt64_kernel<<<dim3(DMODEL / 64, HDIM / 64, NSH), 256, 0, stream>>>(
      sw3, w3t + (size_t)NEXP * DMODEL * HDIM, HDIM, DMODEL);

  gate_kernel<<<TOKENS, 64, 0, stream>>>(x, gate_w, gate_b, topk_idx, topk_w, counts);
  offs_kernel<<<1, 64, 0, stream>>>(counts, offs);
  scatter_kernel<<<TOKENS / 256, 256, 0, stream>>>(topk_idx, offs, cursors,
                                                   row_token, tok_rows);

  gemm1_kernel<<<dim3(TOKENS / 128, HDIM / 64, NGRP), 256, 0, stream>>>(
      xb, w1t, w2t, rb1, sb1, rb2, sb2, offs, row_token, glu);
  gemm2_kernel<<<dim3(TOKENS / 128, DMODEL / 128, NGRP), 256, 0, stream>>>(
      glu, w3t, rb3, sb3, offs, yy);
  reduce_kernel<<<TOKENS / 2, 256, 0, stream>>>(yy, tok_rows, topk_w, out);
}